// Round 2
// baseline (1642.594 us; speedup 1.0000x reference)
//
#include <hip/hip_runtime.h>

// SimpleRNN: B=4096, K=512, U=3, P=5, H=128, L=32, N_SUB=10
// 256 blocks x 512 threads (8 waves), 16 batch rows/block, 1 block/CU.
// Two barriers per step. Wave 7 is the critical wave: head->theta->RK4->
// feat->lift in-register (row-per-lane matches MFMA A-frag layout).
// Outputs ring-buffered in LDS; wave 0 stores them in its shadow.

#define KSTEPS 512
#define NTH 512

typedef short s16x8 __attribute__((ext_vector_type(8)));
typedef float f32x4 __attribute__((ext_vector_type(4)));

__device__ __forceinline__ unsigned short f2bf(float f) {
  union { float f; unsigned u; } v; v.f = f;
  unsigned r = v.u + 0x7FFFu + ((v.u >> 16) & 1u);  // RNE
  return (unsigned short)(r >> 16);
}
__device__ __forceinline__ float ex2(float x) {
#if __has_builtin(__builtin_amdgcn_exp2f)
  return __builtin_amdgcn_exp2f(x);
#else
  return exp2f(x);
#endif
}
__device__ __forceinline__ float rcp_(float x) {
#if __has_builtin(__builtin_amdgcn_rcpf)
  return __builtin_amdgcn_rcpf(x);
#else
  return 1.0f / x;
#endif
}
__device__ __forceinline__ float sigm(float x) {
  return rcp_(1.0f + ex2(-1.44269504088896f * x));
}
__device__ __forceinline__ float tanh_(float x) {
  return fmaf(2.0f, rcp_(1.0f + ex2(-2.88539008177793f * x)), -1.0f);
}
__device__ __forceinline__ f32x4 splat4(float v) { f32x4 r = {v, v, v, v}; return r; }
__device__ __forceinline__ f32x4 MFMA(s16x8 a, s16x8 b, f32x4 c) {
  return __builtin_amdgcn_mfma_f32_16x16x32_bf16(a, b, c, 0, 0, 0);
}
__device__ __forceinline__ s16x8 bfrag_g(const float* __restrict__ src8) {
  s16x8 r;
#pragma unroll
  for (int j = 0; j < 8; ++j) r[j] = (short)f2bf(src8[j]);
  return r;
}

__global__ __launch_bounds__(NTH, 2) void rnn_scan_kernel(
    const float* __restrict__ y0, const float* __restrict__ u_seq,
    const float* __restrict__ dt_seq, const float* __restrict__ lift_W,
    const float* __restrict__ lift_b, const float* __restrict__ W_ih,
    const float* __restrict__ W_hh, const float* __restrict__ b_ih,
    const float* __restrict__ b_hh, const float* __restrict__ head_W,
    const float* __restrict__ head_b, const float* __restrict__ jumpW,
    float* __restrict__ y_out, float* __restrict__ th_out) {
  // canonical A-frag layouts: s_Ah[m][k] (m=batch row, k=h col), s_Ax[m][k]
  __shared__ __align__(16) unsigned short s_Ah[16 * 128];
  __shared__ __align__(16) unsigned short s_Ax[16 * 32];
  __shared__ __align__(16) float s_thr[2][16][8];  // theta ring (+transpose buf)
  __shared__ float s_yr[2][16][5];                 // y ring

  const int tid = threadIdx.x;
  const int w = tid >> 6;       // wave 0..7; wave 7 = critical wave
  const int lane = tid & 63;
  const int quad = lane >> 4;
  const int col = lane & 15;
  const int rr = lane & 15;     // row index for wave-7 row-per-lane work
  const int r0 = blockIdx.x << 4;

  s16x8 zf;
#pragma unroll
  for (int j = 0; j < 8; ++j) zf[j] = 0;

  // ---- B fragments (wave w owns h-cols [16w, 16w+16)) ----
  s16x8 bih_r = bfrag_g(&W_ih[(w * 16 + col) * 32 + quad * 8]);
  s16x8 bih_z = bfrag_g(&W_ih[((8 + w) * 16 + col) * 32 + quad * 8]);
  s16x8 bih_n = bfrag_g(&W_ih[((16 + w) * 16 + col) * 32 + quad * 8]);
  s16x8 bhh_r[4], bhh_z[4], bhh_n[4], bhd[4];
#pragma unroll
  for (int s = 0; s < 4; ++s) {
    bhh_r[s] = bfrag_g(&W_hh[(w * 16 + col) * 128 + s * 32 + quad * 8]);
    bhh_z[s] = bfrag_g(&W_hh[((8 + w) * 16 + col) * 128 + s * 32 + quad * 8]);
    bhh_n[s] = bfrag_g(&W_hh[((16 + w) * 16 + col) * 128 + s * 32 + quad * 8]);
    bhd[s] = (col < 8) ? bfrag_g(&head_W[col * 128 + s * 32 + quad * 8]) : zf;
  }
  s16x8 blft0 = (quad == 0) ? bfrag_g(&lift_W[col * 8]) : zf;
  s16x8 blft1 = (quad == 0) ? bfrag_g(&lift_W[(16 + col) * 8]) : zf;

  const float brz_r = b_ih[w * 16 + col] + b_hh[w * 16 + col];
  const float brz_z = b_ih[128 + w * 16 + col] + b_hh[128 + w * 16 + col];
  const float bn_i = b_ih[256 + w * 16 + col];
  const float bn_h = b_hh[256 + w * 16 + col];
  const float lb0 = lift_b[col], lb1 = lift_b[16 + col];
  const float hb = (col < 8) ? head_b[col] : 0.0f;

  float J[15];
#pragma unroll
  for (int i = 0; i < 15; ++i) J[i] = jumpW[i];

  // persistent state
  f32x4 ar = splat4(brz_r), az = splat4(brz_z);
  f32x4 angi = splat4(bn_i), angh = splat4(bn_h);
  float h_reg[4] = {0.f, 0.f, 0.f, 0.f};
  float y[5] = {0.f, 0.f, 0.f, 0.f, 0.f};
  float uc0 = 0.f, uc1 = 0.f, uc2 = 0.f, dtc = 0.f;
  float un0 = 0.f, un1 = 0.f, un2 = 0.f, dtn = 0.f;

  // ---- prologue: wave 7 loads y0/u(0)/dt(0), builds x(0) ----
  if (w == 7) {
    if (lane < 16) {
      const float* yp = &y0[(r0 + rr) * 5];
#pragma unroll
      for (int i = 0; i < 5; ++i) y[i] = yp[i] + 0.01f;
      const float* up = &u_seq[((size_t)(r0 + rr) * KSTEPS) * 3];
      uc0 = up[0]; uc1 = up[1]; uc2 = up[2];
      dtc = dt_seq[(size_t)(r0 + rr) * KSTEPS];
    }
    s16x8 af = zf;
    if (lane < 16) {
      af[0] = f2bf(uc0); af[1] = f2bf(uc1); af[2] = f2bf(uc2);
      af[3] = f2bf(y[0]); af[4] = f2bf(y[1]); af[5] = f2bf(y[2]);
      af[6] = f2bf(y[3]); af[7] = f2bf(y[4]);
    }
    f32x4 x0 = splat4(lb0), x1 = splat4(lb1);
    x0 = MFMA(af, blft0, x0);
    x1 = MFMA(af, blft1, x1);
#pragma unroll
    for (int i = 0; i < 4; ++i) {
      int row = quad * 4 + i;
      float v0 = x0[i]; s_Ax[row * 32 + col] = f2bf(v0 * sigm(v0));
      float v1 = x1[i]; s_Ax[row * 32 + 16 + col] = f2bf(v1 * sigm(v1));
    }
  }
  __syncthreads();  // acts as B_x(0)

#pragma unroll 1
  for (int k = 0; k < KSTEPS; ++k) {
    // ======== phase 1: gi + gates + h scatter (all waves) ========
    {
      s16x8 xf = *(const s16x8*)&s_Ax[col * 32 + quad * 8];
      ar = MFMA(xf, bih_r, ar);
      az = MFMA(xf, bih_z, az);
      angi = MFMA(xf, bih_n, angi);
    }
    if (w == 7 && lane < 16) {  // prefetch u/dt for step k+1 (early issue)
      int kn = (k + 1 < KSTEPS) ? k + 1 : KSTEPS - 1;
      const float* up = &u_seq[((size_t)(r0 + rr) * KSTEPS + kn) * 3];
      un0 = up[0]; un1 = up[1]; un2 = up[2];
      dtn = dt_seq[(size_t)(r0 + rr) * KSTEPS + kn];
    }
#pragma unroll
    for (int i = 0; i < 4; ++i) {
      float r = sigm(ar[i]);
      float z = sigm(az[i]);
      float n = tanh_(fmaf(r, angh[i], angi[i]));
      float hn = fmaf(z, h_reg[i] - n, n);
      h_reg[i] = hn;
      s_Ah[(quad * 4 + i) * 128 + w * 16 + col] = f2bf(hn);
    }
    ar = splat4(brz_r); az = splat4(brz_z);
    angi = splat4(bn_i); angh = splat4(bn_h);
    __syncthreads();  // B_h: h_k ready

    // ======== phase 2 ========
    s16x8 ah[4];
#pragma unroll
    for (int s = 0; s < 4; ++s)
      ah[s] = *(const s16x8*)&s_Ah[col * 128 + s * 32 + quad * 8];

    if (w == 7) {
      // head (2 independent accumulator chains)
      f32x4 hd0 = splat4(hb), hd1 = splat4(0.0f);
      hd0 = MFMA(ah[0], bhd[0], hd0);
      hd1 = MFMA(ah[1], bhd[1], hd1);
      hd0 = MFMA(ah[2], bhd[2], hd0);
      hd1 = MFMA(ah[3], bhd[3], hd1);
      // own-tile gh(k+1): matrix pipe overlaps the VALU work below
#pragma unroll
      for (int s = 0; s < 4; ++s) {
        ar = MFMA(ah[s], bhh_r[s], ar);
        az = MFMA(ah[s], bhh_z[s], az);
        angh = MFMA(ah[s], bhh_n[s], angh);
      }
      f32x4 hd = hd0 + hd1;
      const int slot = k & 1;
      if (col < 8) {
#pragma unroll
        for (int i = 0; i < 4; ++i) {
          float th = fmaf(2.99f, sigm(hd[i]), 0.01f);
          s_thr[slot][quad * 4 + i][col] = th;
        }
      }
      // theta row-major (same-wave LDS transpose)
      float th[8];
      {
        const f32x4 t0 = *(const f32x4*)&s_thr[slot][rr][0];
        const f32x4 t1 = *(const f32x4*)&s_thr[slot][rr][4];
        th[0] = t0[0]; th[1] = t0[1]; th[2] = t0[2]; th[3] = t0[3];
        th[4] = t1[0]; th[5] = t1[1]; th[6] = t1[2]; th[7] = t1[3];
      }
      // input jump, then RK4 (row-per-lane; lanes>=16 compute harmless dups)
#pragma unroll
      for (int i = 0; i < 5; ++i)
        y[i] += uc0 * J[i] + uc1 * J[5 + i] + uc2 * J[10 + i];
      float hs = dtc * 0.1f;
      float hs2 = hs * 0.5f, hs6 = hs * (1.0f / 6.0f);
      auto RHS = [&th](const float* yy, float* dd) {
        float f1 = fmaf(th[0], yy[0], -th[4] * yy[1]);
        float f2 = fmaf(th[1], yy[1], -th[5] * yy[2]);
        float f3 = fmaf(th[2], yy[2], -th[6] * yy[3]);
        float f4 = fmaf(th[3], yy[3], -th[7] * yy[4]);
        dd[0] = -f1; dd[1] = f1 - f2; dd[2] = f2 - f3;
        dd[3] = f3 - f4; dd[4] = f4;
      };
#pragma unroll 1
      for (int ss = 0; ss < 10; ++ss) {
        float k1[5], k2[5], k3[5], k4[5], t[5];
        RHS(y, k1);
#pragma unroll
        for (int i = 0; i < 5; ++i) t[i] = fmaf(hs2, k1[i], y[i]);
        RHS(t, k2);
#pragma unroll
        for (int i = 0; i < 5; ++i) t[i] = fmaf(hs2, k2[i], y[i]);
        RHS(t, k3);
#pragma unroll
        for (int i = 0; i < 5; ++i) t[i] = fmaf(hs, k3[i], y[i]);
        RHS(t, k4);
#pragma unroll
        for (int i = 0; i < 5; ++i) {
          float acc = fmaf(2.0f, k2[i] + k3[i], k1[i]) + k4[i];
          y[i] = fmaxf(fmaf(hs6, acc, y[i]), 0.0f);
        }
      }
      if (lane < 16) {
#pragma unroll
        for (int i = 0; i < 5; ++i) s_yr[slot][rr][i] = y[i];
      }
      // feat(k+1) in-register -> lift -> x(k+1)
      if (k + 1 < KSTEPS) {
        s16x8 af = zf;
        if (lane < 16) {
          af[0] = f2bf(un0); af[1] = f2bf(un1); af[2] = f2bf(un2);
          af[3] = f2bf(y[0]); af[4] = f2bf(y[1]); af[5] = f2bf(y[2]);
          af[6] = f2bf(y[3]); af[7] = f2bf(y[4]);
        }
        f32x4 x0 = splat4(lb0), x1 = splat4(lb1);
        x0 = MFMA(af, blft0, x0);
        x1 = MFMA(af, blft1, x1);
#pragma unroll
        for (int i = 0; i < 4; ++i) {
          int row = quad * 4 + i;
          float v0 = x0[i]; s_Ax[row * 32 + col] = f2bf(v0 * sigm(v0));
          float v1 = x1[i]; s_Ax[row * 32 + 16 + col] = f2bf(v1 * sigm(v1));
        }
      }
      uc0 = un0; uc1 = un1; uc2 = un2; dtc = dtn;
    } else {
      // gh(k+1) for this wave's tile (runs in wave-7's shadow)
#pragma unroll
      for (int s = 0; s < 4; ++s) {
        ar = MFMA(ah[s], bhh_r[s], ar);
        az = MFMA(ah[s], bhh_z[s], az);
        angh = MFMA(ah[s], bhh_n[s], angh);
      }
      if (w == 0 && k > 0) {  // store step k-1 outputs from the ring
        const int km = k - 1, slot = km & 1;
#pragma unroll
        for (int rep = 0; rep < 2; ++rep) {
          int idx = lane + rep * 64;
          int row = idx >> 3, c = idx & 7;
          th_out[((size_t)(r0 + row) * KSTEPS + km) * 8 + c] = s_thr[slot][row][c];
        }
        {
          int idx = lane;
          int row = idx / 5, c = idx - row * 5;
          y_out[((size_t)(r0 + row) * KSTEPS + km) * 5 + c] = s_yr[slot][row][c];
        }
        if (lane < 16) {
          int idx = 64 + lane;
          int row = idx / 5, c = idx - row * 5;
          y_out[((size_t)(r0 + row) * KSTEPS + km) * 5 + c] = s_yr[slot][row][c];
        }
      }
    }
    __syncthreads();  // B_x: x(k+1) ready, s_Ah safe to overwrite
  }

  // flush outputs of step 511
  if (w == 0) {
    const int km = KSTEPS - 1, slot = km & 1;
#pragma unroll
    for (int rep = 0; rep < 2; ++rep) {
      int idx = lane + rep * 64;
      int row = idx >> 3, c = idx & 7;
      th_out[((size_t)(r0 + row) * KSTEPS + km) * 8 + c] = s_thr[slot][row][c];
    }
    {
      int idx = lane;
      int row = idx / 5, c = idx - row * 5;
      y_out[((size_t)(r0 + row) * KSTEPS + km) * 5 + c] = s_yr[slot][row][c];
    }
    if (lane < 16) {
      int idx = 64 + lane;
      int row = idx / 5, c = idx - row * 5;
      y_out[((size_t)(r0 + row) * KSTEPS + km) * 5 + c] = s_yr[slot][row][c];
    }
  }
}

extern "C" void kernel_launch(void* const* d_in, const int* in_sizes, int n_in,
                              void* d_out, int out_size, void* d_ws, size_t ws_size,
                              hipStream_t stream) {
  const float* y0 = (const float*)d_in[0];
  const float* u_seq = (const float*)d_in[1];
  const float* dt_seq = (const float*)d_in[2];
  const float* lift_W = (const float*)d_in[3];
  const float* lift_b = (const float*)d_in[4];
  const float* W_ih = (const float*)d_in[5];
  const float* W_hh = (const float*)d_in[6];
  const float* b_ih = (const float*)d_in[7];
  const float* b_hh = (const float*)d_in[8];
  const float* head_W = (const float*)d_in[9];
  const float* head_b = (const float*)d_in[10];
  const float* jumpW = (const float*)d_in[11];

  float* y_out = (float*)d_out;                    // (4096, 512, 5)
  float* th_out = y_out + (size_t)4096 * 512 * 5;  // (4096, 512, 8)

  rnn_scan_kernel<<<dim3(256), dim3(NTH), 0, stream>>>(
      y0, u_seq, dt_seq, lift_W, lift_b, W_ih, W_hh, b_ih, b_hh, head_W,
      head_b, jumpW, y_out, th_out);
}

// Round 3
// 1512.562 us; speedup vs baseline: 1.0860x; 1.0860x over previous
//
#include <hip/hip_runtime.h>

// SimpleRNN: B=4096, K=512, U=3, P=5, H=128, L=32, N_SUB=10
// 256 blocks x 512 threads (8 waves), 16 batch rows/block, 1 block/CU.
// "T-scheme": all GEMMs computed transposed (weights as MFMA A-operand,
// activations as B-operand) so D has batch-row in lane&15 and out-col in
// regs. LDS fragment buffers are lane-major: consumer lane l reads its 16B
// block at l*16 (conflict-free b128); producers write one ds_write_b64.
// Theta emerges row-per-lane (quad0=kf, quad1=kr) -> ds_swizzle xor16.

#define KSTEPS 512
#define NTH 512

typedef short s16x8 __attribute__((ext_vector_type(8)));
typedef short s16x4 __attribute__((ext_vector_type(4)));
typedef float f32x4 __attribute__((ext_vector_type(4)));

__device__ __forceinline__ unsigned short f2bf(float f) {
  union { float f; unsigned u; } v; v.f = f;
  unsigned r = v.u + 0x7FFFu + ((v.u >> 16) & 1u);  // RNE
  return (unsigned short)(r >> 16);
}
__device__ __forceinline__ float ex2(float x) {
#if __has_builtin(__builtin_amdgcn_exp2f)
  return __builtin_amdgcn_exp2f(x);
#else
  return exp2f(x);
#endif
}
__device__ __forceinline__ float rcp_(float x) {
#if __has_builtin(__builtin_amdgcn_rcpf)
  return __builtin_amdgcn_rcpf(x);
#else
  return 1.0f / x;
#endif
}
__device__ __forceinline__ float sigm(float x) {
  return rcp_(1.0f + ex2(-1.44269504088896f * x));
}
__device__ __forceinline__ float tanh_(float x) {
  return fmaf(2.0f, rcp_(1.0f + ex2(-2.88539008177793f * x)), -1.0f);
}
__device__ __forceinline__ f32x4 splat4(float v) { f32x4 r = {v, v, v, v}; return r; }
__device__ __forceinline__ f32x4 MFMA(s16x8 a, s16x8 b, f32x4 c) {
  return __builtin_amdgcn_mfma_f32_16x16x32_bf16(a, b, c, 0, 0, 0);
}
__device__ __forceinline__ s16x8 bfrag_g(const float* __restrict__ src8) {
  s16x8 r;
#pragma unroll
  for (int j = 0; j < 8; ++j) r[j] = (short)f2bf(src8[j]);
  return r;
}
__device__ __forceinline__ float swz16(float x) {  // lane <- lane^16
  return __int_as_float(__builtin_amdgcn_ds_swizzle(__float_as_int(x), 0x401F));
}

__global__ __launch_bounds__(NTH, 2) void rnn_scan_kernel(
    const float* __restrict__ y0, const float* __restrict__ u_seq,
    const float* __restrict__ dt_seq, const float* __restrict__ lift_W,
    const float* __restrict__ lift_b, const float* __restrict__ W_ih,
    const float* __restrict__ W_hh, const float* __restrict__ b_ih,
    const float* __restrict__ b_hh, const float* __restrict__ head_W,
    const float* __restrict__ head_b, const float* __restrict__ jumpW,
    float* __restrict__ y_out, float* __restrict__ th_out) {
  // lane-major fragment buffers: block (s*64 + q*16 + row) of 8 shorts holds
  // act[row][s*32 + q*8 .. +7]; consumer lane l frag s reads block s*64+l.
  __shared__ __align__(16) unsigned short s_Ah[4096];  // h: k=128 -> 4 frags
  __shared__ __align__(16) unsigned short s_Ax[1024];  // x: k=32  -> 1 frag
  __shared__ __align__(16) float s_thr[2][16][8];      // theta ring
  __shared__ __align__(16) float s_yr[2][16][8];       // y ring (padded)

  const int tid = threadIdx.x;
  const int w = tid >> 6;      // wave 0..7; wave 7 = critical wave
  const int lane = tid & 63;
  const int quad = lane >> 4;
  const int col = lane & 15;   // = batch row in the T-scheme
  const int r0 = blockIdx.x << 4;

  s16x8 zf;
#pragma unroll
  for (int j = 0; j < 8; ++j) zf[j] = 0;

  // ---- weight A-frags: A[m=out-col@lane&15][k=quad*8+j] ----
  s16x8 bih_r = bfrag_g(&W_ih[(w * 16 + col) * 32 + quad * 8]);
  s16x8 bih_z = bfrag_g(&W_ih[((8 + w) * 16 + col) * 32 + quad * 8]);
  s16x8 bih_n = bfrag_g(&W_ih[((16 + w) * 16 + col) * 32 + quad * 8]);
  s16x8 bhh_r[4], bhh_z[4], bhh_n[4], bhd[4];
#pragma unroll
  for (int s = 0; s < 4; ++s) {
    bhh_r[s] = bfrag_g(&W_hh[(w * 16 + col) * 128 + s * 32 + quad * 8]);
    bhh_z[s] = bfrag_g(&W_hh[((8 + w) * 16 + col) * 128 + s * 32 + quad * 8]);
    bhh_n[s] = bfrag_g(&W_hh[((16 + w) * 16 + col) * 128 + s * 32 + quad * 8]);
    bhd[s] = (col < 8) ? bfrag_g(&head_W[col * 128 + s * 32 + quad * 8]) : zf;
  }
  s16x8 blft0 = (quad == 0) ? bfrag_g(&lift_W[col * 8]) : zf;
  s16x8 blft1 = (quad == 0) ? bfrag_g(&lift_W[(16 + col) * 8]) : zf;

  // ---- per-(quad,i) biases (out-col dim now lives in regs+quad) ----
  f32x4 brz_r, brz_z, bn_iv, bn_hv, lbv0, lbv1, hbv;
#pragma unroll
  for (int i = 0; i < 4; ++i) {
    int g = w * 16 + quad * 4 + i;
    brz_r[i] = b_ih[g] + b_hh[g];
    brz_z[i] = b_ih[128 + g] + b_hh[128 + g];
    bn_iv[i] = b_ih[256 + g];
    bn_hv[i] = b_hh[256 + g];
    lbv0[i] = lift_b[quad * 4 + i];
    lbv1[i] = lift_b[16 + quad * 4 + i];
    hbv[i] = (quad < 2) ? head_b[quad * 4 + i] : 0.0f;
  }
  float J[15];
#pragma unroll
  for (int i = 0; i < 15; ++i) J[i] = jumpW[i];

  // producer LDS byte offsets
  const int hwoff = (((w >> 1) * 64 + ((w & 1) * 2 + (quad >> 1)) * 16 + col) << 4) +
                    ((quad & 1) << 3);
  const int xw0 = ((((quad >> 1)) * 16 + col) << 4) + ((quad & 1) << 3);
  const int xw1 = (((2 + (quad >> 1)) * 16 + col) << 4) + ((quad & 1) << 3);

  // persistent state
  f32x4 ar = brz_r, az = brz_z, angi = bn_iv, angh = bn_hv;
  f32x4 h_reg = splat4(0.0f);
  float y[5] = {0.f, 0.f, 0.f, 0.f, 0.f};
  float uc0 = 0.f, uc1 = 0.f, uc2 = 0.f, dtc = 0.f;
  float un0 = 0.f, un1 = 0.f, un2 = 0.f, dtn = 0.f;

  // ---- prologue: wave 7 builds x(0) ----
  if (w == 7) {
    if (quad == 0) {
      const float* yp = &y0[(r0 + col) * 5];
#pragma unroll
      for (int i = 0; i < 5; ++i) y[i] = yp[i] + 0.01f;
      const float* up = &u_seq[((size_t)(r0 + col) * KSTEPS) * 3];
      uc0 = up[0]; uc1 = up[1]; uc2 = up[2];
      dtc = dt_seq[(size_t)(r0 + col) * KSTEPS];
    }
    s16x8 af = zf;
    if (quad == 0) {
      af[0] = f2bf(uc0); af[1] = f2bf(uc1); af[2] = f2bf(uc2);
      af[3] = f2bf(y[0]); af[4] = f2bf(y[1]); af[5] = f2bf(y[2]);
      af[6] = f2bf(y[3]); af[7] = f2bf(y[4]);
    }
    f32x4 x0 = MFMA(blft0, af, lbv0);
    f32x4 x1 = MFMA(blft1, af, lbv1);
    s16x4 xv0, xv1;
#pragma unroll
    for (int i = 0; i < 4; ++i) {
      float v0 = x0[i]; xv0[i] = (short)f2bf(v0 * sigm(v0));
      float v1 = x1[i]; xv1[i] = (short)f2bf(v1 * sigm(v1));
    }
    *(s16x4*)((char*)s_Ax + xw0) = xv0;
    *(s16x4*)((char*)s_Ax + xw1) = xv1;
  }
  __syncthreads();  // B_x(0)

#pragma unroll 1
  for (int k = 0; k < KSTEPS; ++k) {
    // ======== phase 1: gi + gates + h stage (all waves) ========
    {
      s16x8 xf = *(const s16x8*)((const char*)s_Ax + lane * 16);
      ar = MFMA(bih_r, xf, ar);
      az = MFMA(bih_z, xf, az);
      angi = MFMA(bih_n, xf, angi);
    }
    if (w == 7 && quad == 0) {  // prefetch u/dt for step k+1
      int kn = (k + 1 < KSTEPS) ? k + 1 : KSTEPS - 1;
      const float* up = &u_seq[((size_t)(r0 + col) * KSTEPS + kn) * 3];
      un0 = up[0]; un1 = up[1]; un2 = up[2];
      dtn = dt_seq[(size_t)(r0 + col) * KSTEPS + kn];
    }
    {
      s16x4 hv;
#pragma unroll
      for (int i = 0; i < 4; ++i) {
        float r = sigm(ar[i]);
        float z = sigm(az[i]);
        float n = tanh_(fmaf(r, angh[i], angi[i]));
        float hn = fmaf(z, h_reg[i] - n, n);
        h_reg[i] = hn;
        hv[i] = (short)f2bf(hn);
      }
      *(s16x4*)((char*)s_Ah + hwoff) = hv;  // one b64, ~4-way (free-ish)
    }
    ar = brz_r; az = brz_z; angi = bn_iv; angh = bn_hv;  // reset for k+1
    __syncthreads();  // B_h

    // ======== phase 2 ========
    s16x8 ah[4];
#pragma unroll
    for (int s = 0; s < 4; ++s)
      ah[s] = *(const s16x8*)((const char*)s_Ah + (s * 64 + lane) * 16);

    if (w == 7) {
      // headT: D[m=c][n=row] -> lane(col=row, quad<2) holds th[quad*4+i]
      f32x4 hd0 = MFMA(bhd[0], ah[0], hbv);
      f32x4 hd1 = MFMA(bhd[1], ah[1], splat4(0.0f));
      hd0 = MFMA(bhd[2], ah[2], hd0);
      hd1 = MFMA(bhd[3], ah[3], hd1);
      // own gh(k+1) overlaps the head->theta latency
#pragma unroll
      for (int s = 0; s < 4; ++s) {
        ar = MFMA(bhh_r[s], ah[s], ar);
        az = MFMA(bhh_z[s], ah[s], az);
        angh = MFMA(bhh_n[s], ah[s], angh);
      }
      f32x4 hd = hd0 + hd1;
      f32x4 tv;
#pragma unroll
      for (int i = 0; i < 4; ++i) tv[i] = fmaf(2.99f, sigm(hd[i]), 0.01f);
      const int slot = k & 1;
      if (quad < 2) *(f32x4*)&s_thr[slot][col][quad * 4] = tv;
      // quad0: own tv = kf1..4, swizzled (lane^16) tv = kr1..4
      float th[8];
#pragma unroll
      for (int i = 0; i < 4; ++i) {
        th[i] = tv[i];
        th[4 + i] = swz16(tv[i]);
      }
      // jump + RK4 (uniform execution; valid on quad0, benign elsewhere)
#pragma unroll
      for (int i = 0; i < 5; ++i)
        y[i] += uc0 * J[i] + uc1 * J[5 + i] + uc2 * J[10 + i];
      float hs = dtc * 0.1f;
      float hs2 = hs * 0.5f, hs6 = hs * (1.0f / 6.0f);
      auto RHS = [&th](const float* yy, float* dd) {
        float f1 = fmaf(th[0], yy[0], -th[4] * yy[1]);
        float f2 = fmaf(th[1], yy[1], -th[5] * yy[2]);
        float f3 = fmaf(th[2], yy[2], -th[6] * yy[3]);
        float f4 = fmaf(th[3], yy[3], -th[7] * yy[4]);
        dd[0] = -f1; dd[1] = f1 - f2; dd[2] = f2 - f3;
        dd[3] = f3 - f4; dd[4] = f4;
      };
#pragma unroll 1
      for (int ss = 0; ss < 10; ++ss) {
        float k1[5], k2[5], k3[5], k4[5], t[5];
        RHS(y, k1);
#pragma unroll
        for (int i = 0; i < 5; ++i) t[i] = fmaf(hs2, k1[i], y[i]);
        RHS(t, k2);
#pragma unroll
        for (int i = 0; i < 5; ++i) t[i] = fmaf(hs2, k2[i], y[i]);
        RHS(t, k3);
#pragma unroll
        for (int i = 0; i < 5; ++i) t[i] = fmaf(hs, k3[i], y[i]);
        RHS(t, k4);
#pragma unroll
        for (int i = 0; i < 5; ++i) {
          float acc = fmaf(2.0f, k2[i] + k3[i], k1[i]) + k4[i];
          y[i] = fmaxf(fmaf(hs6, acc, y[i]), 0.0f);
        }
      }
      if (quad == 0) {
        *(f32x4*)&s_yr[slot][col][0] = *(const f32x4*)&y[0];
        s_yr[slot][col][4] = y[4];
      }
      // feat(k+1) -> liftT -> silu -> x stage
      if (k + 1 < KSTEPS) {
        s16x8 af = zf;
        if (quad == 0) {
          af[0] = f2bf(un0); af[1] = f2bf(un1); af[2] = f2bf(un2);
          af[3] = f2bf(y[0]); af[4] = f2bf(y[1]); af[5] = f2bf(y[2]);
          af[6] = f2bf(y[3]); af[7] = f2bf(y[4]);
        }
        f32x4 x0 = MFMA(blft0, af, lbv0);
        f32x4 x1 = MFMA(blft1, af, lbv1);
        s16x4 xv0, xv1;
#pragma unroll
        for (int i = 0; i < 4; ++i) {
          float v0 = x0[i]; xv0[i] = (short)f2bf(v0 * sigm(v0));
          float v1 = x1[i]; xv1[i] = (short)f2bf(v1 * sigm(v1));
        }
        *(s16x4*)((char*)s_Ax + xw0) = xv0;
        *(s16x4*)((char*)s_Ax + xw1) = xv1;
      }
      uc0 = un0; uc1 = un1; uc2 = un2; dtc = dtn;
    } else {
      // gh(k+1) for this wave's tile (in wave-7's shadow)
#pragma unroll
      for (int s = 0; s < 4; ++s) {
        ar = MFMA(bhh_r[s], ah[s], ar);
        az = MFMA(bhh_z[s], ah[s], az);
        angh = MFMA(bhh_n[s], ah[s], angh);
      }
      if (w == 0 && k > 0) {  // store step k-1 outputs from the ring
        const int km = k - 1, slot = km & 1;
#pragma unroll
        for (int rep = 0; rep < 2; ++rep) {
          int idx = lane + rep * 64;
          int row = idx >> 3, c = idx & 7;
          th_out[((size_t)(r0 + row) * KSTEPS + km) * 8 + c] = s_thr[slot][row][c];
        }
        {
          int idx = lane;
          int row = idx / 5, c = idx - row * 5;
          y_out[((size_t)(r0 + row) * KSTEPS + km) * 5 + c] = s_yr[slot][row][c];
        }
        if (lane < 16) {
          int idx = 64 + lane;
          int row = idx / 5, c = idx - row * 5;
          y_out[((size_t)(r0 + row) * KSTEPS + km) * 5 + c] = s_yr[slot][row][c];
        }
      }
    }
    __syncthreads();  // B_x: x(k+1) staged, s_Ah reusable
  }

  // flush step-511 outputs
  if (w == 0) {
    const int km = KSTEPS - 1, slot = km & 1;
#pragma unroll
    for (int rep = 0; rep < 2; ++rep) {
      int idx = lane + rep * 64;
      int row = idx >> 3, c = idx & 7;
      th_out[((size_t)(r0 + row) * KSTEPS + km) * 8 + c] = s_thr[slot][row][c];
    }
    {
      int idx = lane;
      int row = idx / 5, c = idx - row * 5;
      y_out[((size_t)(r0 + row) * KSTEPS + km) * 5 + c] = s_yr[slot][row][c];
    }
    if (lane < 16) {
      int idx = 64 + lane;
      int row = idx / 5, c = idx - row * 5;
      y_out[((size_t)(r0 + row) * KSTEPS + km) * 5 + c] = s_yr[slot][row][c];
    }
  }
}

extern "C" void kernel_launch(void* const* d_in, const int* in_sizes, int n_in,
                              void* d_out, int out_size, void* d_ws, size_t ws_size,
                              hipStream_t stream) {
  const float* y0 = (const float*)d_in[0];
  const float* u_seq = (const float*)d_in[1];
  const float* dt_seq = (const float*)d_in[2];
  const float* lift_W = (const float*)d_in[3];
  const float* lift_b = (const float*)d_in[4];
  const float* W_ih = (const float*)d_in[5];
  const float* W_hh = (const float*)d_in[6];
  const float* b_ih = (const float*)d_in[7];
  const float* b_hh = (const float*)d_in[8];
  const float* head_W = (const float*)d_in[9];
  const float* head_b = (const float*)d_in[10];
  const float* jumpW = (const float*)d_in[11];

  float* y_out = (float*)d_out;                    // (4096, 512, 5)
  float* th_out = y_out + (size_t)4096 * 512 * 5;  // (4096, 512, 8)

  rnn_scan_kernel<<<dim3(256), dim3(NTH), 0, stream>>>(
      y0, u_seq, dt_seq, lift_W, lift_b, W_ih, W_hh, b_ih, b_hh, head_W,
      head_b, jumpW, y_out, th_out);
}